// Round 8
// baseline (250.694 us; speedup 1.0000x reference)
//
#include <hip/hip_runtime.h>
#include <math.h>

#define BB 16
#define CC 256
#define HH 128
#define WW 128
#define HWSZ (HH * WW)   // 16384

typedef float floatx4 __attribute__((ext_vector_type(4)));

// ---------------------------------------------------------------------------
// Kernel 1: channel-wise avg & max pool (R5 version — caching loads so x
// lands in L3 for kernel 2's re-read).
// Tile = 256 pixels. Block = 256 threads = 64 f4-lanes x 4 channel-splits.
// ---------------------------------------------------------------------------
__global__ __launch_bounds__(256) void pool_kernel(const float* __restrict__ x,
                                                   float* __restrict__ avg_out,
                                                   float* __restrict__ max_out) {
    const int tf4   = threadIdx.x & 63;   // f4 group within 256-px tile
    const int split = threadIdx.x >> 6;   // 0..3 channel split
    const int p0    = blockIdx.x * 256;   // first pixel of tile
    const int b     = p0 >> 14;           // tiles never straddle batch
    const int hw    = (p0 & (HWSZ - 1)) + tf4 * 4;

    const float* xb = x + (size_t)b * CC * HWSZ + hw;

    float4 s = make_float4(0.f, 0.f, 0.f, 0.f);
    float4 m = make_float4(-INFINITY, -INFINITY, -INFINITY, -INFINITY);

    const int c0 = split * 64;
    #pragma unroll 8
    for (int i = 0; i < 64; ++i) {
        float4 v = *(const float4*)(xb + (size_t)(c0 + i) * HWSZ);
        s.x += v.x; s.y += v.y; s.z += v.z; s.w += v.w;
        m.x = fmaxf(m.x, v.x); m.y = fmaxf(m.y, v.y);
        m.z = fmaxf(m.z, v.z); m.w = fmaxf(m.w, v.w);
    }

    __shared__ float4 sS[4][64];
    __shared__ float4 sM[4][64];
    sS[split][tf4] = s;
    sM[split][tf4] = m;
    __syncthreads();

    for (int off = 2; off >= 1; off >>= 1) {
        if (split < off) {
            float4 a  = sS[split][tf4], b2 = sS[split + off][tf4];
            a.x += b2.x; a.y += b2.y; a.z += b2.z; a.w += b2.w;
            sS[split][tf4] = a;
            float4 ma = sM[split][tf4], mb = sM[split + off][tf4];
            ma.x = fmaxf(ma.x, mb.x); ma.y = fmaxf(ma.y, mb.y);
            ma.z = fmaxf(ma.z, mb.z); ma.w = fmaxf(ma.w, mb.w);
            sM[split][tf4] = ma;
        }
        __syncthreads();
    }

    if (split == 0) {
        float4 a = sS[0][tf4];
        const float inv = 1.0f / CC;
        a.x *= inv; a.y *= inv; a.z *= inv; a.w *= inv;
        *(float4*)(avg_out + (size_t)b * HWSZ + hw) = a;
        *(float4*)(max_out + (size_t)b * HWSZ + hw) = sM[0][tf4];
    }
}

// ---------------------------------------------------------------------------
// Kernel 2: conv(7x7)+sigmoid fused with broadcast multiply (R5, unchanged).
// MEASUREMENT ROUND: launched TWICE (idempotent) — the run-total delta vs R5
// equals this kernel's duration, finally attributing the 55 µs slack.
// ---------------------------------------------------------------------------
__global__ __launch_bounds__(256) void convmul_kernel(const float* __restrict__ x,
                                                      const float* __restrict__ avg_p,
                                                      const float* __restrict__ max_p,
                                                      const float* __restrict__ wgt,
                                                      float* __restrict__ out) {
    __shared__ float sw[98];
    __shared__ float sMl[256];

    const int tid = threadIdx.x;
    if (tid < 98) sw[tid] = wgt[tid];
    __syncthreads();

    const int strip = blockIdx.x;        // 0..1023
    const int b     = strip >> 6;        // 64 strips per batch
    const int h0    = (strip & 63) * 2;  // strip's first row

    {
        const int hl = tid >> 7;
        const int w  = tid & 127;
        const int h  = h0 + hl;
        const float* ap = avg_p + (size_t)b * HWSZ;
        const float* mp = max_p + (size_t)b * HWSZ;

        float acc = 0.f;
        #pragma unroll
        for (int kh = 0; kh < 7; ++kh) {
            const int hh = h + kh - 3;
            if (hh < 0 || hh >= HH) continue;
            #pragma unroll
            for (int kw = 0; kw < 7; ++kw) {
                const int ww2 = w + kw - 3;
                if (ww2 < 0 || ww2 >= WW) continue;
                const int off = hh * WW + ww2;
                acc += ap[off] * sw[kh * 7 + kw];
                acc += mp[off] * sw[49 + kh * 7 + kw];
            }
        }
        sMl[tid] = 1.0f / (1.0f + expf(-acc));
    }
    __syncthreads();

    const int g    = tid & 63;
    const int csub = tid >> 6;
    const floatx4 mv = ((const floatx4*)sMl)[g];

    const size_t base = (size_t)b * CC * HWSZ + (size_t)h0 * WW + (size_t)g * 4;
    const float* xp = x + base;
    float*       op = out + base;

    #pragma unroll 4
    for (int c = 0; c < 64; ++c) {
        const size_t coff = (size_t)(c * 4 + csub) * HWSZ;
        floatx4 xv = __builtin_nontemporal_load((const floatx4*)(xp + coff));
        __builtin_nontemporal_store(xv * mv, (floatx4*)(op + coff));
    }
}

extern "C" void kernel_launch(void* const* d_in, const int* in_sizes, int n_in,
                              void* d_out, int out_size, void* d_ws, size_t ws_size,
                              hipStream_t stream) {
    const float* x   = (const float*)d_in[0];
    const float* wgt = (const float*)d_in[1];
    float* out = (float*)d_out;

    float* avg_p = (float*)d_ws;                   // 1 MB
    float* max_p = avg_p + (size_t)BB * HWSZ;      // 1 MB

    pool_kernel<<<1024, 256, 0, stream>>>(x, avg_p, max_p);
    // Launched twice on purpose (idempotent): delta vs R5's 145 us = t_convmul.
    convmul_kernel<<<1024, 256, 0, stream>>>(x, avg_p, max_p, wgt, out);
    convmul_kernel<<<1024, 256, 0, stream>>>(x, avg_p, max_p, wgt, out);
}

// Round 9
// 174.351 us; speedup vs baseline: 1.4379x; 1.4379x over previous
//
#include <hip/hip_runtime.h>
#include <math.h>

#define BB 16
#define CC 256
#define HH 128
#define WW 128
#define HWSZ (HH * WW)   // 16384

typedef float floatx4 __attribute__((ext_vector_type(4)));

// ---------------------------------------------------------------------------
// Kernel 1: channel-wise avg & max pool (unchanged — measured at ~40 us,
// i.e. 6.8 TB/s read: at the roofline). Caching loads keep x L3-resident.
// ---------------------------------------------------------------------------
__global__ __launch_bounds__(256) void pool_kernel(const float* __restrict__ x,
                                                   float* __restrict__ avg_out,
                                                   float* __restrict__ max_out) {
    const int tf4   = threadIdx.x & 63;   // f4 group within 256-px tile
    const int split = threadIdx.x >> 6;   // 0..3 channel split
    const int p0    = blockIdx.x * 256;   // first pixel of tile
    const int b     = p0 >> 14;           // tiles never straddle batch
    const int hw    = (p0 & (HWSZ - 1)) + tf4 * 4;

    const float* xb = x + (size_t)b * CC * HWSZ + hw;

    float4 s = make_float4(0.f, 0.f, 0.f, 0.f);
    float4 m = make_float4(-INFINITY, -INFINITY, -INFINITY, -INFINITY);

    const int c0 = split * 64;
    #pragma unroll 8
    for (int i = 0; i < 64; ++i) {
        float4 v = *(const float4*)(xb + (size_t)(c0 + i) * HWSZ);
        s.x += v.x; s.y += v.y; s.z += v.z; s.w += v.w;
        m.x = fmaxf(m.x, v.x); m.y = fmaxf(m.y, v.y);
        m.z = fmaxf(m.z, v.z); m.w = fmaxf(m.w, v.w);
    }

    __shared__ float4 sS[4][64];
    __shared__ float4 sM[4][64];
    sS[split][tf4] = s;
    sM[split][tf4] = m;
    __syncthreads();

    for (int off = 2; off >= 1; off >>= 1) {
        if (split < off) {
            float4 a  = sS[split][tf4], b2 = sS[split + off][tf4];
            a.x += b2.x; a.y += b2.y; a.z += b2.z; a.w += b2.w;
            sS[split][tf4] = a;
            float4 ma = sM[split][tf4], mb = sM[split + off][tf4];
            ma.x = fmaxf(ma.x, mb.x); ma.y = fmaxf(ma.y, mb.y);
            ma.z = fmaxf(ma.z, mb.z); ma.w = fmaxf(ma.w, mb.w);
            sM[split][tf4] = ma;
        }
        __syncthreads();
    }

    if (split == 0) {
        float4 a = sS[0][tf4];
        const float inv = 1.0f / CC;
        a.x *= inv; a.y *= inv; a.z *= inv; a.w *= inv;
        *(float4*)(avg_out + (size_t)b * HWSZ + hw) = a;
        *(float4*)(max_out + (size_t)b * HWSZ + hw) = sM[0][tf4];
    }
}

// ---------------------------------------------------------------------------
// Kernel 2: conv(7x7)+sigmoid fused with broadcast multiply.
// A/B CHANGE vs R5 (single variable): out stores are NORMAL (allocating)
// instead of nontemporal. Fills prove normal streaming stores sustain
// 7 TB/s; hypothesis is the NT-store path capped us at 5.1 TB/s aggregate.
// x loads stay NT (hit L3 without disturbing state).
// ---------------------------------------------------------------------------
__global__ __launch_bounds__(256) void convmul_kernel(const float* __restrict__ x,
                                                      const float* __restrict__ avg_p,
                                                      const float* __restrict__ max_p,
                                                      const float* __restrict__ wgt,
                                                      float* __restrict__ out) {
    __shared__ float sw[98];
    __shared__ float sMl[256];

    const int tid = threadIdx.x;
    if (tid < 98) sw[tid] = wgt[tid];
    __syncthreads();

    const int strip = blockIdx.x;        // 0..1023
    const int b     = strip >> 6;        // 64 strips per batch
    const int h0    = (strip & 63) * 2;  // strip's first row

    // ---- phase a: conv + sigmoid for this strip's 256 pixels ----
    {
        const int hl = tid >> 7;
        const int w  = tid & 127;
        const int h  = h0 + hl;
        const float* ap = avg_p + (size_t)b * HWSZ;
        const float* mp = max_p + (size_t)b * HWSZ;

        float acc = 0.f;
        #pragma unroll
        for (int kh = 0; kh < 7; ++kh) {
            const int hh = h + kh - 3;
            if (hh < 0 || hh >= HH) continue;
            #pragma unroll
            for (int kw = 0; kw < 7; ++kw) {
                const int ww2 = w + kw - 3;
                if (ww2 < 0 || ww2 >= WW) continue;
                const int off = hh * WW + ww2;
                acc += ap[off] * sw[kh * 7 + kw];
                acc += mp[off] * sw[49 + kh * 7 + kw];
            }
        }
        sMl[tid] = 1.0f / (1.0f + expf(-acc));
    }
    __syncthreads();

    // ---- phase b: out = x * M over all 256 channels ----
    const int g    = tid & 63;
    const int csub = tid >> 6;
    const floatx4 mv = ((const floatx4*)sMl)[g];

    const size_t base = (size_t)b * CC * HWSZ + (size_t)h0 * WW + (size_t)g * 4;
    const float* xp = x + base;
    float*       op = out + base;

    #pragma unroll 4
    for (int c = 0; c < 64; ++c) {
        const size_t coff = (size_t)(c * 4 + csub) * HWSZ;
        floatx4 xv = __builtin_nontemporal_load((const floatx4*)(xp + coff));
        *(floatx4*)(op + coff) = xv * mv;   // NORMAL store (the A/B variable)
    }
}

extern "C" void kernel_launch(void* const* d_in, const int* in_sizes, int n_in,
                              void* d_out, int out_size, void* d_ws, size_t ws_size,
                              hipStream_t stream) {
    const float* x   = (const float*)d_in[0];
    const float* wgt = (const float*)d_in[1];
    float* out = (float*)d_out;

    float* avg_p = (float*)d_ws;                   // 1 MB
    float* max_p = avg_p + (size_t)BB * HWSZ;      // 1 MB

    pool_kernel<<<1024, 256, 0, stream>>>(x, avg_p, max_p);
    convmul_kernel<<<1024, 256, 0, stream>>>(x, avg_p, max_p, wgt, out);
}

// Round 10
// 145.481 us; speedup vs baseline: 1.7232x; 1.1984x over previous
//
#include <hip/hip_runtime.h>
#include <math.h>

#define BB 16
#define CC 256
#define HH 128
#define WW 128
#define HWSZ (HH * WW)   // 16384

typedef float floatx4 __attribute__((ext_vector_type(4)));

// ---------------------------------------------------------------------------
// Kernel 1: channel-wise avg & max pool (unchanged — measured ~39.5 us
// incl. launch gap = ~7 TB/s read: at roofline). Caching loads keep x in L3.
// ---------------------------------------------------------------------------
__global__ __launch_bounds__(256) void pool_kernel(const float* __restrict__ x,
                                                   float* __restrict__ avg_out,
                                                   float* __restrict__ max_out) {
    const int tf4   = threadIdx.x & 63;   // f4 group within 256-px tile
    const int split = threadIdx.x >> 6;   // 0..3 channel split
    const int p0    = blockIdx.x * 256;   // first pixel of tile
    const int b     = p0 >> 14;           // tiles never straddle batch
    const int hw    = (p0 & (HWSZ - 1)) + tf4 * 4;

    const float* xb = x + (size_t)b * CC * HWSZ + hw;

    float4 s = make_float4(0.f, 0.f, 0.f, 0.f);
    float4 m = make_float4(-INFINITY, -INFINITY, -INFINITY, -INFINITY);

    const int c0 = split * 64;
    #pragma unroll 8
    for (int i = 0; i < 64; ++i) {
        float4 v = *(const float4*)(xb + (size_t)(c0 + i) * HWSZ);
        s.x += v.x; s.y += v.y; s.z += v.z; s.w += v.w;
        m.x = fmaxf(m.x, v.x); m.y = fmaxf(m.y, v.y);
        m.z = fmaxf(m.z, v.z); m.w = fmaxf(m.w, v.w);
    }

    __shared__ float4 sS[4][64];
    __shared__ float4 sM[4][64];
    sS[split][tf4] = s;
    sM[split][tf4] = m;
    __syncthreads();

    for (int off = 2; off >= 1; off >>= 1) {
        if (split < off) {
            float4 a  = sS[split][tf4], b2 = sS[split + off][tf4];
            a.x += b2.x; a.y += b2.y; a.z += b2.z; a.w += b2.w;
            sS[split][tf4] = a;
            float4 ma = sM[split][tf4], mb = sM[split + off][tf4];
            ma.x = fmaxf(ma.x, mb.x); ma.y = fmaxf(ma.y, mb.y);
            ma.z = fmaxf(ma.z, mb.z); ma.w = fmaxf(ma.w, mb.w);
            sM[split][tf4] = ma;
        }
        __syncthreads();
    }

    if (split == 0) {
        float4 a = sS[0][tf4];
        const float inv = 1.0f / CC;
        a.x *= inv; a.y *= inv; a.z *= inv; a.w *= inv;
        *(float4*)(avg_out + (size_t)b * HWSZ + hw) = a;
        *(float4*)(max_out + (size_t)b * HWSZ + hw) = sM[0][tf4];
    }
}

// ---------------------------------------------------------------------------
// Kernel 2: conv(7x7)+sigmoid fused with broadcast multiply.
// R10 CHANGE (one lever: request concurrency): 2048 blocks — each block =
// (2-row strip) x (channel half). 8 blocks/CU = 32 waves/CU (full occupancy);
// phase-b unrolled 8 -> 8 NT loads in flight per wave. Conv phase computed
// redundantly in both halves (~98 MACs, trivial). NT loads (L3 hits without
// re-allocation) + NT stores (don't evict x) — best known from R5/R7/R9 A/Bs.
// ---------------------------------------------------------------------------
__global__ __launch_bounds__(256) void convmul_kernel(const float* __restrict__ x,
                                                      const float* __restrict__ avg_p,
                                                      const float* __restrict__ max_p,
                                                      const float* __restrict__ wgt,
                                                      float* __restrict__ out) {
    __shared__ float sw[98];
    __shared__ float sMl[256];

    const int tid = threadIdx.x;
    if (tid < 98) sw[tid] = wgt[tid];
    __syncthreads();

    const int bid   = blockIdx.x;        // 0..2047
    const int hc    = bid & 1;           // channel half: 0 -> c0..127, 1 -> c128..255
    const int strip = bid >> 1;          // 0..1023
    const int b     = strip >> 6;        // 64 strips per batch
    const int h0    = (strip & 63) * 2;  // strip's first row

    // ---- phase a: conv + sigmoid for this strip's 256 pixels ----
    {
        const int hl = tid >> 7;
        const int w  = tid & 127;
        const int h  = h0 + hl;
        const float* ap = avg_p + (size_t)b * HWSZ;
        const float* mp = max_p + (size_t)b * HWSZ;

        float acc = 0.f;
        #pragma unroll
        for (int kh = 0; kh < 7; ++kh) {
            const int hh = h + kh - 3;
            if (hh < 0 || hh >= HH) continue;
            #pragma unroll
            for (int kw = 0; kw < 7; ++kw) {
                const int ww2 = w + kw - 3;
                if (ww2 < 0 || ww2 >= WW) continue;
                const int off = hh * WW + ww2;
                acc += ap[off] * sw[kh * 7 + kw];
                acc += mp[off] * sw[49 + kh * 7 + kw];
            }
        }
        sMl[tid] = 1.0f / (1.0f + expf(-acc));
    }
    __syncthreads();

    // ---- phase b: out = x * M over this block's 128 channels ----
    const int g    = tid & 63;            // f4 group within strip (64 x 4 px)
    const int csub = tid >> 6;            // 0..3
    const floatx4 mv = ((const floatx4*)sMl)[g];

    const size_t base = (size_t)b * CC * HWSZ
                      + (size_t)(hc * 128 + csub) * HWSZ
                      + (size_t)h0 * WW + (size_t)g * 4;
    const float* xp = x + base;
    float*       op = out + base;

    #pragma unroll 8
    for (int c = 0; c < 32; ++c) {
        const size_t coff = (size_t)c * 4 * HWSZ;   // advance 4 channels/iter
        floatx4 xv = __builtin_nontemporal_load((const floatx4*)(xp + coff));
        __builtin_nontemporal_store(xv * mv, (floatx4*)(op + coff));
    }
}

extern "C" void kernel_launch(void* const* d_in, const int* in_sizes, int n_in,
                              void* d_out, int out_size, void* d_ws, size_t ws_size,
                              hipStream_t stream) {
    const float* x   = (const float*)d_in[0];
    const float* wgt = (const float*)d_in[1];
    float* out = (float*)d_out;

    float* avg_p = (float*)d_ws;                   // 1 MB
    float* max_p = avg_p + (size_t)BB * HWSZ;      // 1 MB

    pool_kernel<<<1024, 256, 0, stream>>>(x, avg_p, max_p);
    convmul_kernel<<<2048, 256, 0, stream>>>(x, avg_p, max_p, wgt, out);
}

// Round 11
// 142.080 us; speedup vs baseline: 1.7645x; 1.0239x over previous
//
#include <hip/hip_runtime.h>
#include <math.h>

#define BB 16
#define CC 256
#define HH 128
#define WW 128
#define HWSZ (HH * WW)   // 16384

typedef float floatx4 __attribute__((ext_vector_type(4)));

// ---------------------------------------------------------------------------
// Kernel 1: channel-wise avg & max pool (unchanged — measured ~39.5 us
// = ~7 TB/s read, at roofline). Caching loads keep x L3-resident for K2.
// ---------------------------------------------------------------------------
__global__ __launch_bounds__(256) void pool_kernel(const float* __restrict__ x,
                                                   float* __restrict__ avg_out,
                                                   float* __restrict__ max_out) {
    const int tf4   = threadIdx.x & 63;   // f4 group within 256-px tile
    const int split = threadIdx.x >> 6;   // 0..3 channel split
    const int p0    = blockIdx.x * 256;   // first pixel of tile
    const int b     = p0 >> 14;           // tiles never straddle batch
    const int hw    = (p0 & (HWSZ - 1)) + tf4 * 4;

    const float* xb = x + (size_t)b * CC * HWSZ + hw;

    float4 s = make_float4(0.f, 0.f, 0.f, 0.f);
    float4 m = make_float4(-INFINITY, -INFINITY, -INFINITY, -INFINITY);

    const int c0 = split * 64;
    #pragma unroll 8
    for (int i = 0; i < 64; ++i) {
        float4 v = *(const float4*)(xb + (size_t)(c0 + i) * HWSZ);
        s.x += v.x; s.y += v.y; s.z += v.z; s.w += v.w;
        m.x = fmaxf(m.x, v.x); m.y = fmaxf(m.y, v.y);
        m.z = fmaxf(m.z, v.z); m.w = fmaxf(m.w, v.w);
    }

    __shared__ float4 sS[4][64];
    __shared__ float4 sM[4][64];
    sS[split][tf4] = s;
    sM[split][tf4] = m;
    __syncthreads();

    for (int off = 2; off >= 1; off >>= 1) {
        if (split < off) {
            float4 a  = sS[split][tf4], b2 = sS[split + off][tf4];
            a.x += b2.x; a.y += b2.y; a.z += b2.z; a.w += b2.w;
            sS[split][tf4] = a;
            float4 ma = sM[split][tf4], mb = sM[split + off][tf4];
            ma.x = fmaxf(ma.x, mb.x); ma.y = fmaxf(ma.y, mb.y);
            ma.z = fmaxf(ma.z, mb.z); ma.w = fmaxf(ma.w, mb.w);
            sM[split][tf4] = ma;
        }
        __syncthreads();
    }

    if (split == 0) {
        float4 a = sS[0][tf4];
        const float inv = 1.0f / CC;
        a.x *= inv; a.y *= inv; a.z *= inv; a.w *= inv;
        *(float4*)(avg_out + (size_t)b * HWSZ + hw) = a;
        *(float4*)(max_out + (size_t)b * HWSZ + hw) = sM[0][tf4];
    }
}

// ---------------------------------------------------------------------------
// Kernel 2: conv(7x7)+sigmoid fused with broadcast multiply.
// R11 A/B (single variable vs R5): x loads are NORMAL (caching) instead of
// nontemporal; stores stay NT. Hypothesis: NT loads bypass L2 allocation and
// issue 64B fabric requests instead of L2-mediated 128B line fills, capping
// the read side — m13's plain copy (normal loads) sustains 6.3 TB/s mixed
// where we got 5.1. Normal loads still hit x in L3; L2 pollution is harmless
// for read-once data. NT stores keep protecting x's L3 residency (R9 lesson).
// ---------------------------------------------------------------------------
__global__ __launch_bounds__(256) void convmul_kernel(const float* __restrict__ x,
                                                      const float* __restrict__ avg_p,
                                                      const float* __restrict__ max_p,
                                                      const float* __restrict__ wgt,
                                                      float* __restrict__ out) {
    __shared__ float sw[98];
    __shared__ float sMl[256];

    const int tid = threadIdx.x;
    if (tid < 98) sw[tid] = wgt[tid];
    __syncthreads();

    const int strip = blockIdx.x;        // 0..1023
    const int b     = strip >> 6;        // 64 strips per batch
    const int h0    = (strip & 63) * 2;  // strip's first row

    // ---- phase a: conv + sigmoid for this strip's 256 pixels ----
    {
        const int hl = tid >> 7;
        const int w  = tid & 127;
        const int h  = h0 + hl;
        const float* ap = avg_p + (size_t)b * HWSZ;
        const float* mp = max_p + (size_t)b * HWSZ;

        float acc = 0.f;
        #pragma unroll
        for (int kh = 0; kh < 7; ++kh) {
            const int hh = h + kh - 3;
            if (hh < 0 || hh >= HH) continue;
            #pragma unroll
            for (int kw = 0; kw < 7; ++kw) {
                const int ww2 = w + kw - 3;
                if (ww2 < 0 || ww2 >= WW) continue;
                const int off = hh * WW + ww2;
                acc += ap[off] * sw[kh * 7 + kw];
                acc += mp[off] * sw[49 + kh * 7 + kw];
            }
        }
        sMl[tid] = 1.0f / (1.0f + expf(-acc));
    }
    __syncthreads();

    // ---- phase b: out = x * M over all 256 channels ----
    const int g    = tid & 63;            // f4 group within strip (64 x 4 px)
    const int csub = tid >> 6;            // 0..3
    const floatx4 mv = ((const floatx4*)sMl)[g];

    const size_t base = (size_t)b * CC * HWSZ + (size_t)h0 * WW + (size_t)g * 4;
    const float* xp = x + base;
    float*       op = out + base;

    #pragma unroll 4
    for (int c = 0; c < 64; ++c) {
        const size_t coff = (size_t)(c * 4 + csub) * HWSZ;
        floatx4 xv = *(const floatx4*)(xp + coff);   // NORMAL load (the A/B variable)
        __builtin_nontemporal_store(xv * mv, (floatx4*)(op + coff));
    }
}

extern "C" void kernel_launch(void* const* d_in, const int* in_sizes, int n_in,
                              void* d_out, int out_size, void* d_ws, size_t ws_size,
                              hipStream_t stream) {
    const float* x   = (const float*)d_in[0];
    const float* wgt = (const float*)d_in[1];
    float* out = (float*)d_out;

    float* avg_p = (float*)d_ws;                   // 1 MB
    float* max_p = avg_p + (size_t)BB * HWSZ;      // 1 MB

    pool_kernel<<<1024, 256, 0, stream>>>(x, avg_p, max_p);
    convmul_kernel<<<1024, 256, 0, stream>>>(x, avg_p, max_p, wgt, out);
}